// Round 1
// baseline (3519.225 us; speedup 1.0000x reference)
//
#include <hip/hip_runtime.h>
#include <cmath>

// Problem constants
#define NIMG 5
#define CCH  256
#define HHH  128
#define WWW  128
#define HW   16384            // 128*128
#define NPIX 81920            // 5*16384
#define SF_ELEMS 20971520     // 5*256*16384
#define LOSS_OFF 20971520
#define RATE_OFF 20971521
#define MASK_OFF 20971522

typedef __attribute__((ext_vector_type(4))) float f32x4;
typedef __attribute__((ext_vector_type(8))) __bf16 bf16x8;

__device__ __forceinline__ unsigned short f32_to_bf16(float f) {
  unsigned int u = __float_as_uint(f);
  u += 0x7FFFu + ((u >> 16) & 1u);   // round-to-nearest-even
  return (unsigned short)(u >> 16);
}

__device__ __forceinline__ double sigmoid_d(double x) { return 1.0 / (1.0 + exp(-x)); }

__device__ __forceinline__ float softplus_f(float x) {
  if (x > 20.f) return x;
  if (x < -20.f) return expf(x);
  return log1pf(expf(x));
}

// g2 kernel value, computed as numpy does (f64 then cast f32), promoted back to double
__device__ __forceinline__ double g2w(int ky, int kx) {
  int d2 = (ky - 1) * (ky - 1) + (kx - 1) * (kx - 1);
  double g = 0.15915494309189535 * exp(-0.5 * (double)d2);
  return (double)(float)g;
}

// ---------------- K0: zero accumulators ----------------
__global__ void k0_init(double* S1, double* S2, unsigned long long* cnt) {
  if (threadIdx.x == 0 && blockIdx.x == 0) { *S1 = 0.0; *S2 = 0.0; *cnt = 0ull; }
}

// ---------------- K1: per-(n,c) mean & max over HW ----------------
__global__ void k1_rednc(const float* __restrict__ feat, double* __restrict__ avg_d,
                         double* __restrict__ mx_d) {
  int nc = blockIdx.x;            // 0..1279
  int t = threadIdx.x;            // 256 threads
  const float* p = feat + (size_t)nc * HW;
  double s = 0.0;
  float m = -3.4e38f;
  for (int i = t; i < HW; i += 256) { float v = p[i]; s += (double)v; m = fmaxf(m, v); }
  __shared__ double sd[256];
  __shared__ float sm[256];
  sd[t] = s; sm[t] = m;
  __syncthreads();
  for (int o = 128; o > 0; o >>= 1) {
    if (t < o) { sd[t] += sd[t + o]; sm[t] = fmaxf(sm[t], sm[t + o]); }
    __syncthreads();
  }
  if (t == 0) { avg_d[nc] = sd[0] / 16384.0; mx_d[nc] = (double)sm[0]; }
}

// ---------------- K2: per-(n,p) channel mean & max ----------------
__global__ void k2_rednp(const float* __restrict__ feat, double* __restrict__ chmean,
                         double* __restrict__ chmax) {
  int gid = blockIdx.x * 256 + threadIdx.x;   // 0..81919
  int n = gid >> 14, p = gid & (HW - 1);
  const float* base = feat + (size_t)n * CCH * HW + p;
  double s = 0.0;
  float m = -3.4e38f;
  for (int c = 0; c < CCH; ++c) { float v = base[(size_t)c * HW]; s += (double)v; m = fmaxf(m, v); }
  chmean[gid] = s / 256.0;
  chmax[gid] = (double)m;
}

// ---------------- K3: channel-attention MLP + fusion + 1d conv (one block) -------
__global__ void k3_chan(const double* __restrict__ avg_d, const double* __restrict__ mx_d,
                        const float* __restrict__ w1, const float* __restrict__ w2,
                        const float* __restrict__ fus, double* __restrict__ chcoef_d) {
  __shared__ double hid_a[NIMG][16], hid_m[NIMG][16];
  __shared__ double att[NIMG][CCH];
  __shared__ double sig[4][CCH];
  int t = threadIdx.x;   // 256 threads, t = channel
  if (t < NIMG * 16) {
    int n = t / 16, j = t % 16;
    double sa = 0.0, sx = 0.0;
    for (int c = 0; c < CCH; ++c) {
      double w = (double)w1[j * CCH + c];
      sa += avg_d[n * CCH + c] * w;
      sx += mx_d[n * CCH + c] * w;
    }
    hid_a[n][j] = sa > 0.0 ? sa : 0.0;
    hid_m[n][j] = sx > 0.0 ? sx : 0.0;
  }
  __syncthreads();
  for (int n = 0; n < NIMG; ++n) {
    double oa = 0.0, om = 0.0;
    for (int j = 0; j < 16; ++j) {
      double w = (double)w2[t * 16 + j];
      oa += hid_a[n][j] * w;
      om += hid_m[n][j] * w;
    }
    att[n][t] = sigmoid_d(oa + om);
  }
  __syncthreads();
  for (int m = 0; m < 4; ++m) {
    double s = 0.0;
    for (int k = 0; k < CCH; ++k) {
      s += (1.0 - att[0][k]) * (double)fus[t * 512 + k]
         + att[m + 1][k] * (double)fus[t * 512 + 256 + k];
    }
    sig[m][t] = sigmoid_d(s);
  }
  __syncthreads();
  // g1, computed as numpy float32 does
  float a32 = (float)exp(-0.5);
  float s32 = (a32 + 1.0f) + a32;
  double ge = (double)(a32 / s32);
  double gc = (double)(1.0f / s32);
  for (int m = 0; m < 4; ++m) {
    double L = (t > 0) ? sig[m][t - 1] : 0.0;
    double R = (t < 255) ? sig[m][t + 1] : 0.0;
    chcoef_d[m * CCH + t] = ge * L + gc * sig[m][t] + ge * R;
  }
}

// ---------------- K4: spatial attention conv + act (gaussian of sigmoid(mean)) ----
__global__ void k4_spatial(const double* __restrict__ chmean, const double* __restrict__ chmax,
                           const float* __restrict__ spw, double* __restrict__ spatt,
                           double* __restrict__ actb) {
  int gid = blockIdx.x * 256 + threadIdx.x;   // 0..81919
  int n = gid >> 14, p = gid & (HW - 1);
  int y = p >> 7, x = p & 127;
  const double* cm = chmean + (size_t)n * HW;
  const double* cx = chmax + (size_t)n * HW;
  double s = 0.0, a = 0.0;
  for (int ky = 0; ky < 3; ++ky) {
    int yy = y + ky - 1;
    if ((unsigned)yy >= 128u) continue;
    for (int kx = 0; kx < 3; ++kx) {
      int xx = x + kx - 1;
      if ((unsigned)xx >= 128u) continue;
      int q = (yy << 7) + xx;
      s += (double)spw[ky * 3 + kx] * cm[q] + (double)spw[9 + ky * 3 + kx] * cx[q];
      a += g2w(ky, kx) * sigmoid_d(cm[q]);
    }
  }
  spatt[gid] = sigmoid_d(s);
  actb[gid] = a;
}

// ---------------- K5a: spatial fusion sigmoid ----------------
__global__ void k5a_spsig(const double* __restrict__ spatt, const float* __restrict__ fus2,
                          double* __restrict__ spsig) {
  int gid = blockIdx.x * 256 + threadIdx.x;   // 0..65535
  int m = gid >> 14, p = gid & (HW - 1);
  double wa = (double)fus2[0], wb = (double)fus2[1];
  double ego = 1.0 - spatt[p];                // n = 0
  spsig[gid] = sigmoid_d(wa * ego + wb * spatt[(size_t)(m + 1) * HW + p]);
}

// ---------------- K5b: gaussian conv of sp_sig, times act[m+1] ----------------
__global__ void k5b_spcoef(const double* __restrict__ spsig, const double* __restrict__ actb,
                           double* __restrict__ spact) {
  int gid = blockIdx.x * 256 + threadIdx.x;   // 0..65535
  int m = gid >> 14, p = gid & (HW - 1);
  int y = p >> 7, x = p & 127;
  const double* sp = spsig + (size_t)m * HW;
  double s = 0.0;
  for (int ky = 0; ky < 3; ++ky) {
    int yy = y + ky - 1;
    if ((unsigned)yy >= 128u) continue;
    for (int kx = 0; kx < 3; ++kx) {
      int xx = x + kx - 1;
      if ((unsigned)xx >= 128u) continue;
      s += g2w(ky, kx) * sp[(yy << 7) + xx];
    }
  }
  spact[gid] = s * actb[(size_t)(m + 1) * HW + p];
}

// ---------------- K6: mask + sparse_feature + sparse_mask + count ----------------
__global__ void k6_mask(const float* __restrict__ feat, const double* __restrict__ chcoef,
                        const double* __restrict__ spact, float* __restrict__ out_sf,
                        float* __restrict__ out_mask, unsigned long long* __restrict__ cnt) {
  __shared__ unsigned long long wsum[4];
  int bid = blockIdx.x, t = threadIdx.x;
  int nc = bid >> 6;
  int p = ((bid & 63) << 8) + t;
  size_t e = (size_t)nc * HW + p;
  int n = nc >> 8, c = nc & 255;
  float v = feat[e];
  if (n == 0) {                 // uniform per block: no divergence across the block
    out_sf[e] = v;
    out_mask[e] = 1.0f;
    return;
  }
  double sm = chcoef[(n - 1) * CCH + c] * spact[(size_t)(n - 1) * HW + p];
  float mk = (sm > 0.01) ? 1.0f : 0.0f;
  out_sf[e] = v * mk;
  out_mask[e] = mk;
  unsigned long long bal = __ballot(mk != 0.0f);
  if ((t & 63) == 0) wsum[t >> 6] = (unsigned long long)__popcll(bal);
  __syncthreads();
  if (t == 0) atomicAdd(cnt, wsum[0] + wsum[1] + wsum[2] + wsum[3]);
}

// ---------------- K7: weight conversion f32 -> bf16 ----------------
__global__ void k7_wconv(const float* __restrict__ w1, const float* __restrict__ w2,
                         unsigned short* __restrict__ W1b, unsigned short* __restrict__ W2b) {
  int gid = blockIdx.x * 256 + threadIdx.x;   // 0..1048575
  if (gid < 524288) W1b[gid] = f32_to_bf16(w1[gid]);
  W2b[gid] = f32_to_bf16(w2[gid]);
}

// ---------------- K8: fused stat MLP (layer1+layer2+layer3+softplus reduce) -------
// 32 pixels per block, branch 0 = T (joint), branch 1 = T' (marginal).
// LDS (64 KiB): region reused: xcat[32][520] (bf16 bits) during layer1,
// then h1[32][1024] (XOR-swizzled bf16) for layer2, then t_acc/red scraps.
__global__ __launch_bounds__(256, 2) void k8_stat(
    const float* __restrict__ feat, const float* __restrict__ dout,
    const unsigned short* __restrict__ W1b, const unsigned short* __restrict__ W2b,
    const float* __restrict__ b1, const float* __restrict__ b2,
    const float* __restrict__ w3, const float* __restrict__ b3,
    double* __restrict__ S1, double* __restrict__ S2) {
  __shared__ unsigned short lds[32768];   // exactly 64 KiB
  float* t_acc = (float*)lds;             // bytes [0,128)   (reused after layer2)
  float* red = (float*)(lds + 64);        // bytes [128,256)

  const int bid = blockIdx.x;
  const int n = bid >> 9;                 // 512 tiles per image
  const int p0 = (bid & 511) << 5;        // 32 pixels per tile
  const int n1 = (n + 1 == NIMG) ? 0 : (n + 1);

  const int t = threadIdx.x;              // 256 threads = 4 waves; t also = channel
  const int lane = t & 63;
  const int wave = t >> 6;
  const int n16 = lane & 15;
  const int quad = lane >> 4;

  const float b3f = b3[0];
  const float* maskbase = dout + MASK_OFF;

  for (int br = 0; br < 2; ++br) {
    // ---- stage xcat: [p][0:256] = feat[src], [p][256:512] = feat[n]*mask (= sf[n])
    {
      const int src = br ? n1 : n;
      const float* fp = feat + ((size_t)src * CCH + t) * HW + p0;
      const float* gp = feat + ((size_t)n * CCH + t) * HW + p0;
      if (n == 0) {
        for (int p = 0; p < 32; ++p) {
          lds[p * 520 + t] = f32_to_bf16(fp[p]);
          lds[p * 520 + 256 + t] = f32_to_bf16(gp[p]);
        }
      } else {
        const float* mp = maskbase + ((size_t)n * CCH + t) * HW + p0;
        for (int p = 0; p < 32; ++p) {
          lds[p * 520 + t] = f32_to_bf16(fp[p]);
          lds[p * 520 + 256 + t] = f32_to_bf16(gp[p] * mp[p]);
        }
      }
    }
    __syncthreads();

    // ---- layer 1: h1 = relu(x @ W1^T + b1), x is 32x512, W1 is 1024x512
    f32x4 acc0[16], acc1[16];
    {
      f32x4 z = {0.f, 0.f, 0.f, 0.f};
#pragma unroll
      for (int i = 0; i < 16; ++i) { acc0[i] = z; acc1[i] = z; }
    }
    {
      const int arow0 = n16 * 520;
      const int arow1 = (16 + n16) * 520;
      const int obase = wave * 256 + n16;
      for (int ks = 0; ks < 16; ++ks) {
        const int kb = ks * 32 + quad * 8;
        bf16x8 a0 = *(const bf16x8*)&lds[arow0 + kb];
        bf16x8 a1 = *(const bf16x8*)&lds[arow1 + kb];
#pragma unroll
        for (int i = 0; i < 16; ++i) {
          bf16x8 b = *(const bf16x8*)&W1b[(size_t)(obase + i * 16) * 512 + kb];
          acc0[i] = __builtin_amdgcn_mfma_f32_16x16x32_bf16(a0, b, acc0[i], 0, 0, 0);
          acc1[i] = __builtin_amdgcn_mfma_f32_16x16x32_bf16(a1, b, acc1[i], 0, 0, 0);
        }
      }
    }
    __syncthreads();   // all waves done reading xcat; safe to overwrite with h1

    // ---- epilogue 1: bias+relu -> h1 (XOR-swizzled by pixel row, stride 1024)
#pragma unroll
    for (int i = 0; i < 16; ++i) {
      const int o = wave * 256 + i * 16 + n16;
      const float bv = b1[o];
      const int oblk = o >> 3, olo = o & 7;
#pragma unroll
      for (int r = 0; r < 4; ++r) {
        const int pr0 = quad * 4 + r;
        const int pr1 = pr0 + 16;
        float v0 = acc0[i][r] + bv; v0 = v0 > 0.f ? v0 : 0.f;
        float v1 = acc1[i][r] + bv; v1 = v1 > 0.f ? v1 : 0.f;
        lds[pr0 * 1024 + (((oblk ^ (pr0 & 7)) << 3) | olo)] = f32_to_bf16(v0);
        lds[pr1 * 1024 + (((oblk ^ (pr1 & 7)) << 3) | olo)] = f32_to_bf16(v1);
      }
    }
    __syncthreads();

    // ---- layer 2: h2 = relu(h1 @ W2^T + b2), fused layer 3 dot with w3
    {
      f32x4 z = {0.f, 0.f, 0.f, 0.f};
#pragma unroll
      for (int i = 0; i < 16; ++i) { acc0[i] = z; acc1[i] = z; }
    }
    {
      const int r0 = n16, r1 = 16 + n16;
      const int obase = wave * 256 + n16;
      for (int ks = 0; ks < 32; ++ks) {
        const int kblk = ks * 4 + quad;
        const int kb = ks * 32 + quad * 8;
        bf16x8 a0 = *(const bf16x8*)&lds[r0 * 1024 + ((kblk ^ (r0 & 7)) << 3)];
        bf16x8 a1 = *(const bf16x8*)&lds[r1 * 1024 + ((kblk ^ (r1 & 7)) << 3)];
#pragma unroll
        for (int i = 0; i < 16; ++i) {
          bf16x8 b = *(const bf16x8*)&W2b[(size_t)(obase + i * 16) * 1024 + kb];
          acc0[i] = __builtin_amdgcn_mfma_f32_16x16x32_bf16(a0, b, acc0[i], 0, 0, 0);
          acc1[i] = __builtin_amdgcn_mfma_f32_16x16x32_bf16(a1, b, acc1[i], 0, 0, 0);
        }
      }
    }
    __syncthreads();   // all waves done reading h1; safe to reuse bytes [0,256)
    if (t < 32) t_acc[t] = 0.f;
    __syncthreads();

    // ---- epilogue 2: relu(acc+b2) dot w3 per pixel
    {
      float tp0[4] = {0.f, 0.f, 0.f, 0.f}, tp1[4] = {0.f, 0.f, 0.f, 0.f};
#pragma unroll
      for (int i = 0; i < 16; ++i) {
        const int o = wave * 256 + i * 16 + n16;
        const float bv = b2[o];
        const float wv = w3[o];
#pragma unroll
        for (int r = 0; r < 4; ++r) {
          float v0 = acc0[i][r] + bv; v0 = v0 > 0.f ? v0 : 0.f;
          float v1 = acc1[i][r] + bv; v1 = v1 > 0.f ? v1 : 0.f;
          tp0[r] += v0 * wv;
          tp1[r] += v1 * wv;
        }
      }
#pragma unroll
      for (int r = 0; r < 4; ++r) {
        atomicAdd(&t_acc[quad * 4 + r], tp0[r]);
        atomicAdd(&t_acc[16 + quad * 4 + r], tp1[r]);
      }
    }
    __syncthreads();
    if (t < 32) {
      float T = t_acc[t] + b3f;
      red[t] = softplus_f(br ? T : -T);
    }
    __syncthreads();
    if (t == 0) {
      float s = 0.f;
#pragma unroll
      for (int p = 0; p < 32; ++p) s += red[p];
      atomicAdd(br ? S2 : S1, (double)s);
    }
    __syncthreads();
  }
}

// ---------------- K9: finalize scalars ----------------
__global__ void k9_final(const double* __restrict__ S1, const double* __restrict__ S2,
                         const unsigned long long* __restrict__ cnt, float* __restrict__ out) {
  if (threadIdx.x == 0 && blockIdx.x == 0) {
    out[LOSS_OFF] = (float)(((*S1) + (*S2)) / 81920.0);
    out[RATE_OFF] = (float)((double)(*cnt) / 16777216.0);
  }
}

extern "C" void kernel_launch(void* const* d_in, const int* in_sizes, int n_in,
                              void* d_out, int out_size, void* d_ws, size_t ws_size,
                              hipStream_t stream) {
  const float* feat     = (const float*)d_in[0];
  const float* mlp_w1   = (const float*)d_in[1];
  const float* mlp_w2   = (const float*)d_in[2];
  const float* sp_req_w = (const float*)d_in[3];
  const float* ch_fus_w = (const float*)d_in[4];
  const float* sp_fus_w = (const float*)d_in[5];
  const float* st_w1    = (const float*)d_in[6];
  const float* st_b1    = (const float*)d_in[7];
  const float* st_w2    = (const float*)d_in[8];
  const float* st_b2    = (const float*)d_in[9];
  const float* st_w3    = (const float*)d_in[10];
  const float* st_b3    = (const float*)d_in[11];
  float* out = (float*)d_out;

  char* ws = (char*)d_ws;
  double* S1     = (double*)(ws + 0);
  double* S2     = (double*)(ws + 8);
  unsigned long long* cnt = (unsigned long long*)(ws + 16);
  double* avg_d  = (double*)(ws + 64);        // 1280
  double* mx_d   = (double*)(ws + 10304);     // 1280
  double* chmean = (double*)(ws + 20544);     // 81920
  double* chmax  = (double*)(ws + 675904);    // 81920
  double* spatt  = (double*)(ws + 1331264);   // 81920
  double* actb   = (double*)(ws + 1986624);   // 81920
  double* chcoef = (double*)(ws + 2652224);   // 1024
  double* spsig  = (double*)(ws + 2660416);   // 65536
  double* spact  = (double*)(ws + 3184704);   // 65536
  unsigned short* W1b = (unsigned short*)(ws + 3708992);  // 524288
  unsigned short* W2b = (unsigned short*)(ws + 4757568);  // 1048576

  k0_init<<<1, 64, 0, stream>>>(S1, S2, cnt);
  k1_rednc<<<1280, 256, 0, stream>>>(feat, avg_d, mx_d);
  k2_rednp<<<320, 256, 0, stream>>>(feat, chmean, chmax);
  k3_chan<<<1, 256, 0, stream>>>(avg_d, mx_d, mlp_w1, mlp_w2, ch_fus_w, chcoef);
  k4_spatial<<<320, 256, 0, stream>>>(chmean, chmax, sp_req_w, spatt, actb);
  k5a_spsig<<<256, 256, 0, stream>>>(spatt, sp_fus_w, spsig);
  k5b_spcoef<<<256, 256, 0, stream>>>(spsig, actb, spact);
  k7_wconv<<<4096, 256, 0, stream>>>(st_w1, st_w2, W1b, W2b);
  k6_mask<<<81920, 256, 0, stream>>>(feat, chcoef, spact, out, out + MASK_OFF, cnt);
  k8_stat<<<2560, 256, 0, stream>>>(feat, out, W1b, W2b, st_b1, st_b2, st_w3, st_b3, S1, S2);
  k9_final<<<1, 64, 0, stream>>>(S1, S2, cnt, out);
}

// Round 2
// 2933.697 us; speedup vs baseline: 1.1996x; 1.1996x over previous
//
#include <hip/hip_runtime.h>
#include <cmath>

// Problem constants
#define NIMG 5
#define CCH  256
#define HHH  128
#define WWW  128
#define HW   16384            // 128*128
#define NPIX 81920            // 5*16384
#define SF_ELEMS 20971520     // 5*256*16384
#define LOSS_OFF 20971520
#define RATE_OFF 20971521
#define MASK_OFF 20971522

typedef __attribute__((ext_vector_type(4))) float f32x4;
typedef __attribute__((ext_vector_type(8))) __bf16 bf16x8;

__device__ __forceinline__ unsigned short f32_to_bf16(float f) {
  unsigned int u = __float_as_uint(f);
  u += 0x7FFFu + ((u >> 16) & 1u);   // round-to-nearest-even
  return (unsigned short)(u >> 16);
}

__device__ __forceinline__ double sigmoid_d(double x) { return 1.0 / (1.0 + exp(-x)); }

__device__ __forceinline__ float softplus_f(float x) {
  if (x > 20.f) return x;
  if (x < -20.f) return expf(x);
  return log1pf(expf(x));
}

// g2 kernel value, computed as numpy does (f64 then cast f32), promoted back to double
__device__ __forceinline__ double g2w(int ky, int kx) {
  int d2 = (ky - 1) * (ky - 1) + (kx - 1) * (kx - 1);
  double g = 0.15915494309189535 * exp(-0.5 * (double)d2);
  return (double)(float)g;
}

// ---------------- K0: zero accumulators ----------------
__global__ void k0_init(double* S1, double* S2, unsigned long long* cnt) {
  if (threadIdx.x == 0 && blockIdx.x == 0) { *S1 = 0.0; *S2 = 0.0; *cnt = 0ull; }
}

// ---------------- K1: per-(n,c) mean & max over HW ----------------
__global__ void k1_rednc(const float* __restrict__ feat, double* __restrict__ avg_d,
                         double* __restrict__ mx_d) {
  int nc = blockIdx.x;            // 0..1279
  int t = threadIdx.x;            // 256 threads
  const float* p = feat + (size_t)nc * HW;
  double s = 0.0;
  float m = -3.4e38f;
  for (int i = t; i < HW; i += 256) { float v = p[i]; s += (double)v; m = fmaxf(m, v); }
  __shared__ double sd[256];
  __shared__ float sm[256];
  sd[t] = s; sm[t] = m;
  __syncthreads();
  for (int o = 128; o > 0; o >>= 1) {
    if (t < o) { sd[t] += sd[t + o]; sm[t] = fmaxf(sm[t], sm[t + o]); }
    __syncthreads();
  }
  if (t == 0) { avg_d[nc] = sd[0] / 16384.0; mx_d[nc] = (double)sm[0]; }
}

// ---------------- K2: per-(n,p) channel mean & max ----------------
__global__ void k2_rednp(const float* __restrict__ feat, double* __restrict__ chmean,
                         double* __restrict__ chmax) {
  int gid = blockIdx.x * 256 + threadIdx.x;   // 0..81919
  int n = gid >> 14, p = gid & (HW - 1);
  const float* base = feat + (size_t)n * CCH * HW + p;
  double s = 0.0;
  float m = -3.4e38f;
  for (int c = 0; c < CCH; ++c) { float v = base[(size_t)c * HW]; s += (double)v; m = fmaxf(m, v); }
  chmean[gid] = s / 256.0;
  chmax[gid] = (double)m;
}

// ---------------- K3: channel-attention MLP + fusion + 1d conv (one block) -------
__global__ void k3_chan(const double* __restrict__ avg_d, const double* __restrict__ mx_d,
                        const float* __restrict__ w1, const float* __restrict__ w2,
                        const float* __restrict__ fus, double* __restrict__ chcoef_d) {
  __shared__ double hid_a[NIMG][16], hid_m[NIMG][16];
  __shared__ double att[NIMG][CCH];
  __shared__ double sig[4][CCH];
  int t = threadIdx.x;   // 256 threads, t = channel
  if (t < NIMG * 16) {
    int n = t / 16, j = t % 16;
    double sa = 0.0, sx = 0.0;
    for (int c = 0; c < CCH; ++c) {
      double w = (double)w1[j * CCH + c];
      sa += avg_d[n * CCH + c] * w;
      sx += mx_d[n * CCH + c] * w;
    }
    hid_a[n][j] = sa > 0.0 ? sa : 0.0;
    hid_m[n][j] = sx > 0.0 ? sx : 0.0;
  }
  __syncthreads();
  for (int n = 0; n < NIMG; ++n) {
    double oa = 0.0, om = 0.0;
    for (int j = 0; j < 16; ++j) {
      double w = (double)w2[t * 16 + j];
      oa += hid_a[n][j] * w;
      om += hid_m[n][j] * w;
    }
    att[n][t] = sigmoid_d(oa + om);
  }
  __syncthreads();
  for (int m = 0; m < 4; ++m) {
    double s = 0.0;
    for (int k = 0; k < CCH; ++k) {
      s += (1.0 - att[0][k]) * (double)fus[t * 512 + k]
         + att[m + 1][k] * (double)fus[t * 512 + 256 + k];
    }
    sig[m][t] = sigmoid_d(s);
  }
  __syncthreads();
  // g1, computed as numpy float32 does
  float a32 = (float)exp(-0.5);
  float s32 = (a32 + 1.0f) + a32;
  double ge = (double)(a32 / s32);
  double gc = (double)(1.0f / s32);
  for (int m = 0; m < 4; ++m) {
    double L = (t > 0) ? sig[m][t - 1] : 0.0;
    double R = (t < 255) ? sig[m][t + 1] : 0.0;
    chcoef_d[m * CCH + t] = ge * L + gc * sig[m][t] + ge * R;
  }
}

// ---------------- K4: spatial attention conv + act (gaussian of sigmoid(mean)) ----
__global__ void k4_spatial(const double* __restrict__ chmean, const double* __restrict__ chmax,
                           const float* __restrict__ spw, double* __restrict__ spatt,
                           double* __restrict__ actb) {
  int gid = blockIdx.x * 256 + threadIdx.x;   // 0..81919
  int n = gid >> 14, p = gid & (HW - 1);
  int y = p >> 7, x = p & 127;
  const double* cm = chmean + (size_t)n * HW;
  const double* cx = chmax + (size_t)n * HW;
  double s = 0.0, a = 0.0;
  for (int ky = 0; ky < 3; ++ky) {
    int yy = y + ky - 1;
    if ((unsigned)yy >= 128u) continue;
    for (int kx = 0; kx < 3; ++kx) {
      int xx = x + kx - 1;
      if ((unsigned)xx >= 128u) continue;
      int q = (yy << 7) + xx;
      s += (double)spw[ky * 3 + kx] * cm[q] + (double)spw[9 + ky * 3 + kx] * cx[q];
      a += g2w(ky, kx) * sigmoid_d(cm[q]);
    }
  }
  spatt[gid] = sigmoid_d(s);
  actb[gid] = a;
}

// ---------------- K5a: spatial fusion sigmoid ----------------
__global__ void k5a_spsig(const double* __restrict__ spatt, const float* __restrict__ fus2,
                          double* __restrict__ spsig) {
  int gid = blockIdx.x * 256 + threadIdx.x;   // 0..65535
  int m = gid >> 14, p = gid & (HW - 1);
  double wa = (double)fus2[0], wb = (double)fus2[1];
  double ego = 1.0 - spatt[p];                // n = 0
  spsig[gid] = sigmoid_d(wa * ego + wb * spatt[(size_t)(m + 1) * HW + p]);
}

// ---------------- K5b: gaussian conv of sp_sig, times act[m+1] ----------------
__global__ void k5b_spcoef(const double* __restrict__ spsig, const double* __restrict__ actb,
                           double* __restrict__ spact) {
  int gid = blockIdx.x * 256 + threadIdx.x;   // 0..65535
  int m = gid >> 14, p = gid & (HW - 1);
  int y = p >> 7, x = p & 127;
  const double* sp = spsig + (size_t)m * HW;
  double s = 0.0;
  for (int ky = 0; ky < 3; ++ky) {
    int yy = y + ky - 1;
    if ((unsigned)yy >= 128u) continue;
    for (int kx = 0; kx < 3; ++kx) {
      int xx = x + kx - 1;
      if ((unsigned)xx >= 128u) continue;
      s += g2w(ky, kx) * sp[(yy << 7) + xx];
    }
  }
  spact[gid] = s * actb[(size_t)(m + 1) * HW + p];
}

// ---------------- K6: mask + sparse_feature + sparse_mask + count ----------------
// Grid-stride, float4 per thread per iter. Counts only n>0 mask bits.
__global__ void k6_mask(const float* __restrict__ feat, const double* __restrict__ chcoef,
                        const double* __restrict__ spact, float* __restrict__ out_sf,
                        float* __restrict__ out_mask, unsigned long long* __restrict__ cnt) {
  const int nth = gridDim.x * blockDim.x;
  int cl = 0;
  for (int g4 = blockIdx.x * blockDim.x + threadIdx.x; g4 < SF_ELEMS / 4; g4 += nth) {
    size_t e = (size_t)g4 * 4;
    int nc = (int)(e >> 14);
    int p = (int)(e & (HW - 1));
    int n = nc >> 8, c = nc & 255;
    f32x4 v = *(const f32x4*)&feat[e];
    f32x4 mk;
    if (n == 0) {
      mk = (f32x4){1.f, 1.f, 1.f, 1.f};
    } else {
      double cc = chcoef[(n - 1) * CCH + c];
      const double* sp = &spact[(size_t)(n - 1) * HW + p];
#pragma unroll
      for (int l = 0; l < 4; ++l) {
        float m = (cc * sp[l] > 0.01) ? 1.f : 0.f;
        mk[l] = m;
        cl += (m != 0.f);
      }
    }
    f32x4 o;
#pragma unroll
    for (int l = 0; l < 4; ++l) o[l] = v[l] * mk[l];
    *(f32x4*)&out_sf[e] = o;
    *(f32x4*)&out_mask[e] = mk;
  }
#pragma unroll
  for (int off = 32; off > 0; off >>= 1) cl += __shfl_down(cl, off);
  if ((threadIdx.x & 63) == 0 && cl > 0) atomicAdd(cnt, (unsigned long long)cl);
}

// ---------------- K7: weight conversion f32 -> bf16 ----------------
__global__ void k7_wconv(const float* __restrict__ w1, const float* __restrict__ w2,
                         unsigned short* __restrict__ W1b, unsigned short* __restrict__ W2b) {
  int gid = blockIdx.x * 256 + threadIdx.x;   // 0..1048575
  if (gid < 524288) W1b[gid] = f32_to_bf16(w1[gid]);
  W2b[gid] = f32_to_bf16(w2[gid]);
}

// ---------------- K8 v2: fused stat MLP, M=64 pixels/block, branch-split ----------
// 512 threads = 8 waves. LDS: xcat 64x512 bf16 (64KB, XOR-swizzled) +
// h1 chunk 64x256 bf16 (32KB, XOR-swizzled) + t_acc (256B) = ~96.5 KB -> 1 blk/CU.
// Layer1 computed in 4 N-chunks of 256; layer2 K-accumulated per chunk.
// Each B-fragment (global, L2-resident) feeds 4 MFMAs (4 pixel row-groups).

__device__ __forceinline__ int xidx(int p, int c) {      // xcat: row-stride 512, 16B-chunk XOR swizzle
  return p * 512 + ((((c >> 3) ^ (p & 7)) << 3) | (c & 7));
}
__device__ __forceinline__ int hidx(int p, int oc) {     // h1 chunk: row-stride 256
  return 32768 + p * 256 + ((((oc >> 3) ^ (p & 7)) << 3) | (oc & 7));
}

__global__ __launch_bounds__(512, 2) void k8_stat(
    const float* __restrict__ feat, const float* __restrict__ dout,
    const unsigned short* __restrict__ W1b, const unsigned short* __restrict__ W2b,
    const float* __restrict__ b1, const float* __restrict__ b2,
    const float* __restrict__ w3, const float* __restrict__ b3,
    double* __restrict__ S1, double* __restrict__ S2) {
  __shared__ unsigned short lds[49408];          // 98816 B
  float* t_acc = (float*)&lds[49152];            // 64 floats

  const int bid = blockIdx.x;
  const int br = bid & 1;
  const int tile = bid >> 1;                     // 0..1279
  const int n = tile >> 8;                       // 256 tiles of 64 px per image
  const int p0 = (tile & 255) << 6;
  const int n1 = (n + 1 == NIMG) ? 0 : n + 1;

  const int t = threadIdx.x;
  const int lane = t & 63;
  const int w = t >> 6;                          // wave 0..7
  const int n16 = lane & 15;
  const int quad = lane >> 4;

  // ---- stage xcat: [p][c<256] = feat[src], [p][c>=256] = feat[n]*mask
  {
    const int c = t;
    const f32x4* s4;
    const f32x4* m4 = nullptr;
    if (c < 256) {
      const int s = br ? n1 : n;
      s4 = (const f32x4*)(feat + ((size_t)s * CCH + c) * HW + p0);
    } else {
      const int cc = c - 256;
      s4 = (const f32x4*)(feat + ((size_t)n * CCH + cc) * HW + p0);
      m4 = (const f32x4*)(dout + MASK_OFF + ((size_t)n * CCH + cc) * HW + p0);
    }
    if (t < 64) t_acc[t] = 0.f;
#pragma unroll 4
    for (int i = 0; i < 16; ++i) {
      f32x4 v = s4[i];
      if (m4) {
        f32x4 mm = m4[i];
#pragma unroll
        for (int l = 0; l < 4; ++l) v[l] *= mm[l];
      }
#pragma unroll
      for (int l = 0; l < 4; ++l) lds[xidx(i * 4 + l, c)] = f32_to_bf16(v[l]);
    }
  }
  __syncthreads();

  f32x4 acc2[4][8];
  {
    f32x4 z = {0.f, 0.f, 0.f, 0.f};
#pragma unroll
    for (int g = 0; g < 4; ++g)
#pragma unroll
      for (int j = 0; j < 8; ++j) acc2[g][j] = z;
  }

  for (int nc = 0; nc < 4; ++nc) {
    // ---- layer1 N-chunk: outputs o in [nc*256, nc*256+256); wave covers 32 cols
    f32x4 acc1[4][2];
    {
      f32x4 z = {0.f, 0.f, 0.f, 0.f};
#pragma unroll
      for (int g = 0; g < 4; ++g) { acc1[g][0] = z; acc1[g][1] = z; }
    }
    for (int ks = 0; ks < 16; ++ks) {
      const int cb = ks * 32 + quad * 8;
      bf16x8 a[4];
#pragma unroll
      for (int g = 0; g < 4; ++g) a[g] = *(const bf16x8*)&lds[xidx(n16 + g * 16, cb)];
#pragma unroll
      for (int j = 0; j < 2; ++j) {
        const int o = nc * 256 + w * 32 + j * 16 + n16;
        bf16x8 b = *(const bf16x8*)&W1b[(size_t)o * 512 + cb];
#pragma unroll
        for (int g = 0; g < 4; ++g)
          acc1[g][j] = __builtin_amdgcn_mfma_f32_16x16x32_bf16(a[g], b, acc1[g][j], 0, 0, 0);
      }
    }
    __syncthreads();   // previous chunk's layer2 done reading h1c

    // ---- epilogue1: bias+relu -> h1 chunk (bf16, swizzled)
#pragma unroll
    for (int j = 0; j < 2; ++j) {
      const int ol = w * 32 + j * 16 + n16;
      const float bv = b1[nc * 256 + ol];
#pragma unroll
      for (int g = 0; g < 4; ++g) {
#pragma unroll
        for (int r = 0; r < 4; ++r) {
          const int row = g * 16 + quad * 4 + r;
          float v = acc1[g][j][r] + bv;
          v = v > 0.f ? v : 0.f;
          lds[hidx(row, ol)] = f32_to_bf16(v);
        }
      }
    }
    __syncthreads();

    // ---- layer2 partial: K-slice [nc*256, nc*256+256); wave covers 128 cols
    for (int ksl = 0; ksl < 8; ++ksl) {
      const int ocb = ksl * 32 + quad * 8;
      const int kg = nc * 256 + ocb;
      bf16x8 a[4];
#pragma unroll
      for (int g = 0; g < 4; ++g) a[g] = *(const bf16x8*)&lds[hidx(n16 + g * 16, ocb)];
#pragma unroll
      for (int jt = 0; jt < 8; ++jt) {
        const int o2 = w * 128 + jt * 16 + n16;
        bf16x8 b = *(const bf16x8*)&W2b[(size_t)o2 * 1024 + kg];
#pragma unroll
        for (int g = 0; g < 4; ++g)
          acc2[g][jt] = __builtin_amdgcn_mfma_f32_16x16x32_bf16(a[g], b, acc2[g][jt], 0, 0, 0);
      }
    }
  }

  // ---- epilogue2: relu(acc2+b2) dot w3, reduce over cols
  float tp[4][4];
#pragma unroll
  for (int g = 0; g < 4; ++g)
#pragma unroll
    for (int r = 0; r < 4; ++r) tp[g][r] = 0.f;
#pragma unroll
  for (int jt = 0; jt < 8; ++jt) {
    const int o2 = w * 128 + jt * 16 + n16;
    const float bv = b2[o2];
    const float wv = w3[o2];
#pragma unroll
    for (int g = 0; g < 4; ++g) {
#pragma unroll
      for (int r = 0; r < 4; ++r) {
        float v = acc2[g][jt][r] + bv;
        v = v > 0.f ? v : 0.f;
        tp[g][r] += v * wv;
      }
    }
  }
#pragma unroll
  for (int off = 1; off < 16; off <<= 1) {
#pragma unroll
    for (int g = 0; g < 4; ++g)
#pragma unroll
      for (int r = 0; r < 4; ++r) tp[g][r] += __shfl_xor(tp[g][r], off);
  }
  if (n16 == 0) {
#pragma unroll
    for (int g = 0; g < 4; ++g)
#pragma unroll
      for (int r = 0; r < 4; ++r) atomicAdd(&t_acc[g * 16 + quad * 4 + r], tp[g][r]);
  }
  __syncthreads();

  if (t < 64) {
    const float T = t_acc[t] + b3[0];
    float v = softplus_f(br ? T : -T);
#pragma unroll
    for (int off = 32; off > 0; off >>= 1) v += __shfl_down(v, off);
    if (t == 0) atomicAdd(br ? S2 : S1, (double)v);
  }
}

// ---------------- K9: finalize scalars ----------------
__global__ void k9_final(const double* __restrict__ S1, const double* __restrict__ S2,
                         const unsigned long long* __restrict__ cnt, float* __restrict__ out) {
  if (threadIdx.x == 0 && blockIdx.x == 0) {
    out[LOSS_OFF] = (float)(((*S1) + (*S2)) / 81920.0);
    out[RATE_OFF] = (float)((double)(*cnt) / 16777216.0);
  }
}

extern "C" void kernel_launch(void* const* d_in, const int* in_sizes, int n_in,
                              void* d_out, int out_size, void* d_ws, size_t ws_size,
                              hipStream_t stream) {
  const float* feat     = (const float*)d_in[0];
  const float* mlp_w1   = (const float*)d_in[1];
  const float* mlp_w2   = (const float*)d_in[2];
  const float* sp_req_w = (const float*)d_in[3];
  const float* ch_fus_w = (const float*)d_in[4];
  const float* sp_fus_w = (const float*)d_in[5];
  const float* st_w1    = (const float*)d_in[6];
  const float* st_b1    = (const float*)d_in[7];
  const float* st_w2    = (const float*)d_in[8];
  const float* st_b2    = (const float*)d_in[9];
  const float* st_w3    = (const float*)d_in[10];
  const float* st_b3    = (const float*)d_in[11];
  float* out = (float*)d_out;

  char* ws = (char*)d_ws;
  double* S1     = (double*)(ws + 0);
  double* S2     = (double*)(ws + 8);
  unsigned long long* cnt = (unsigned long long*)(ws + 16);
  double* avg_d  = (double*)(ws + 64);        // 1280
  double* mx_d   = (double*)(ws + 10304);     // 1280
  double* chmean = (double*)(ws + 20544);     // 81920
  double* chmax  = (double*)(ws + 675904);    // 81920
  double* spatt  = (double*)(ws + 1331264);   // 81920
  double* actb   = (double*)(ws + 1986624);   // 81920
  double* chcoef = (double*)(ws + 2652224);   // 1024
  double* spsig  = (double*)(ws + 2660416);   // 65536
  double* spact  = (double*)(ws + 3184704);   // 65536
  unsigned short* W1b = (unsigned short*)(ws + 3708992);  // 524288
  unsigned short* W2b = (unsigned short*)(ws + 4757568);  // 1048576

  k0_init<<<1, 64, 0, stream>>>(S1, S2, cnt);
  k1_rednc<<<1280, 256, 0, stream>>>(feat, avg_d, mx_d);
  k2_rednp<<<320, 256, 0, stream>>>(feat, chmean, chmax);
  k3_chan<<<1, 256, 0, stream>>>(avg_d, mx_d, mlp_w1, mlp_w2, ch_fus_w, chcoef);
  k4_spatial<<<320, 256, 0, stream>>>(chmean, chmax, sp_req_w, spatt, actb);
  k5a_spsig<<<256, 256, 0, stream>>>(spatt, sp_fus_w, spsig);
  k5b_spcoef<<<256, 256, 0, stream>>>(spsig, actb, spact);
  k7_wconv<<<4096, 256, 0, stream>>>(st_w1, st_w2, W1b, W2b);
  k6_mask<<<2048, 256, 0, stream>>>(feat, chcoef, spact, out, out + MASK_OFF, cnt);
  k8_stat<<<2560, 512, 0, stream>>>(feat, out, W1b, W2b, st_b1, st_b2, st_w3, st_b3, S1, S2);
  k9_final<<<1, 64, 0, stream>>>(S1, S2, cnt, out);
}

// Round 3
// 2356.204 us; speedup vs baseline: 1.4936x; 1.2451x over previous
//
#include <hip/hip_runtime.h>
#include <cmath>

// Problem constants
#define NIMG 5
#define CCH  256
#define HHH  128
#define WWW  128
#define HW   16384            // 128*128
#define NPIX 81920            // 5*16384
#define SF_ELEMS 20971520     // 5*256*16384
#define LOSS_OFF 20971520
#define RATE_OFF 20971521
#define MASK_OFF 20971522

typedef __attribute__((ext_vector_type(4))) float f32x4;
typedef __attribute__((ext_vector_type(8))) __bf16 bf16x8;

__device__ __forceinline__ unsigned short f32_to_bf16(float f) {
  unsigned int u = __float_as_uint(f);
  u += 0x7FFFu + ((u >> 16) & 1u);   // round-to-nearest-even
  return (unsigned short)(u >> 16);
}

__device__ __forceinline__ double sigmoid_d(double x) { return 1.0 / (1.0 + exp(-x)); }

__device__ __forceinline__ float softplus_f(float x) {
  if (x > 20.f) return x;
  if (x < -20.f) return expf(x);
  return log1pf(expf(x));
}

// g2 kernel value, computed as numpy does (f64 then cast f32), promoted back to double
__device__ __forceinline__ double g2w(int ky, int kx) {
  int d2 = (ky - 1) * (ky - 1) + (kx - 1) * (kx - 1);
  double g = 0.15915494309189535 * exp(-0.5 * (double)d2);
  return (double)(float)g;
}

// ---------------- K0: zero accumulators ----------------
__global__ void k0_init(double* S1, double* S2, unsigned long long* cnt) {
  if (threadIdx.x == 0 && blockIdx.x == 0) { *S1 = 0.0; *S2 = 0.0; *cnt = 0ull; }
}

// ---------------- K1: per-(n,c) mean & max over HW ----------------
__global__ void k1_rednc(const float* __restrict__ feat, double* __restrict__ avg_d,
                         double* __restrict__ mx_d) {
  int nc = blockIdx.x;            // 0..1279
  int t = threadIdx.x;            // 256 threads
  const float* p = feat + (size_t)nc * HW;
  double s = 0.0;
  float m = -3.4e38f;
  for (int i = t; i < HW; i += 256) { float v = p[i]; s += (double)v; m = fmaxf(m, v); }
  __shared__ double sd[256];
  __shared__ float sm[256];
  sd[t] = s; sm[t] = m;
  __syncthreads();
  for (int o = 128; o > 0; o >>= 1) {
    if (t < o) { sd[t] += sd[t + o]; sm[t] = fmaxf(sm[t], sm[t + o]); }
    __syncthreads();
  }
  if (t == 0) { avg_d[nc] = sd[0] / 16384.0; mx_d[nc] = (double)sm[0]; }
}

// ---------------- K2: per-(n,p) channel mean & max ----------------
__global__ void k2_rednp(const float* __restrict__ feat, double* __restrict__ chmean,
                         double* __restrict__ chmax) {
  int gid = blockIdx.x * 256 + threadIdx.x;   // 0..81919
  int n = gid >> 14, p = gid & (HW - 1);
  const float* base = feat + (size_t)n * CCH * HW + p;
  double s = 0.0;
  float m = -3.4e38f;
  for (int c = 0; c < CCH; ++c) { float v = base[(size_t)c * HW]; s += (double)v; m = fmaxf(m, v); }
  chmean[gid] = s / 256.0;
  chmax[gid] = (double)m;
}

// ---------------- K3: channel-attention MLP + fusion + 1d conv (one block) -------
__global__ void k3_chan(const double* __restrict__ avg_d, const double* __restrict__ mx_d,
                        const float* __restrict__ w1, const float* __restrict__ w2,
                        const float* __restrict__ fus, double* __restrict__ chcoef_d) {
  __shared__ double hid_a[NIMG][16], hid_m[NIMG][16];
  __shared__ double att[NIMG][CCH];
  __shared__ double sig[4][CCH];
  int t = threadIdx.x;   // 256 threads, t = channel
  if (t < NIMG * 16) {
    int n = t / 16, j = t % 16;
    double sa = 0.0, sx = 0.0;
    for (int c = 0; c < CCH; ++c) {
      double w = (double)w1[j * CCH + c];
      sa += avg_d[n * CCH + c] * w;
      sx += mx_d[n * CCH + c] * w;
    }
    hid_a[n][j] = sa > 0.0 ? sa : 0.0;
    hid_m[n][j] = sx > 0.0 ? sx : 0.0;
  }
  __syncthreads();
  for (int n = 0; n < NIMG; ++n) {
    double oa = 0.0, om = 0.0;
    for (int j = 0; j < 16; ++j) {
      double w = (double)w2[t * 16 + j];
      oa += hid_a[n][j] * w;
      om += hid_m[n][j] * w;
    }
    att[n][t] = sigmoid_d(oa + om);
  }
  __syncthreads();
  for (int m = 0; m < 4; ++m) {
    double s = 0.0;
    for (int k = 0; k < CCH; ++k) {
      s += (1.0 - att[0][k]) * (double)fus[t * 512 + k]
         + att[m + 1][k] * (double)fus[t * 512 + 256 + k];
    }
    sig[m][t] = sigmoid_d(s);
  }
  __syncthreads();
  // g1, computed as numpy float32 does
  float a32 = (float)exp(-0.5);
  float s32 = (a32 + 1.0f) + a32;
  double ge = (double)(a32 / s32);
  double gc = (double)(1.0f / s32);
  for (int m = 0; m < 4; ++m) {
    double L = (t > 0) ? sig[m][t - 1] : 0.0;
    double R = (t < 255) ? sig[m][t + 1] : 0.0;
    chcoef_d[m * CCH + t] = ge * L + gc * sig[m][t] + ge * R;
  }
}

// ---------------- K4: spatial attention conv + act (gaussian of sigmoid(mean)) ----
__global__ void k4_spatial(const double* __restrict__ chmean, const double* __restrict__ chmax,
                           const float* __restrict__ spw, double* __restrict__ spatt,
                           double* __restrict__ actb) {
  int gid = blockIdx.x * 256 + threadIdx.x;   // 0..81919
  int n = gid >> 14, p = gid & (HW - 1);
  int y = p >> 7, x = p & 127;
  const double* cm = chmean + (size_t)n * HW;
  const double* cx = chmax + (size_t)n * HW;
  double s = 0.0, a = 0.0;
  for (int ky = 0; ky < 3; ++ky) {
    int yy = y + ky - 1;
    if ((unsigned)yy >= 128u) continue;
    for (int kx = 0; kx < 3; ++kx) {
      int xx = x + kx - 1;
      if ((unsigned)xx >= 128u) continue;
      int q = (yy << 7) + xx;
      s += (double)spw[ky * 3 + kx] * cm[q] + (double)spw[9 + ky * 3 + kx] * cx[q];
      a += g2w(ky, kx) * sigmoid_d(cm[q]);
    }
  }
  spatt[gid] = sigmoid_d(s);
  actb[gid] = a;
}

// ---------------- K5a: spatial fusion sigmoid ----------------
__global__ void k5a_spsig(const double* __restrict__ spatt, const float* __restrict__ fus2,
                          double* __restrict__ spsig) {
  int gid = blockIdx.x * 256 + threadIdx.x;   // 0..65535
  int m = gid >> 14, p = gid & (HW - 1);
  double wa = (double)fus2[0], wb = (double)fus2[1];
  double ego = 1.0 - spatt[p];                // n = 0
  spsig[gid] = sigmoid_d(wa * ego + wb * spatt[(size_t)(m + 1) * HW + p]);
}

// ---------------- K5b: gaussian conv of sp_sig, times act[m+1] ----------------
__global__ void k5b_spcoef(const double* __restrict__ spsig, const double* __restrict__ actb,
                           double* __restrict__ spact) {
  int gid = blockIdx.x * 256 + threadIdx.x;   // 0..65535
  int m = gid >> 14, p = gid & (HW - 1);
  int y = p >> 7, x = p & 127;
  const double* sp = spsig + (size_t)m * HW;
  double s = 0.0;
  for (int ky = 0; ky < 3; ++ky) {
    int yy = y + ky - 1;
    if ((unsigned)yy >= 128u) continue;
    for (int kx = 0; kx < 3; ++kx) {
      int xx = x + kx - 1;
      if ((unsigned)xx >= 128u) continue;
      s += g2w(ky, kx) * sp[(yy << 7) + xx];
    }
  }
  spact[gid] = s * actb[(size_t)(m + 1) * HW + p];
}

// ---------------- K6: mask + sparse_feature + sparse_mask + count ----------------
// Grid-stride, float4, nontemporal feat loads and output stores (protect L2 for weights).
__global__ void k6_mask(const float* __restrict__ feat, const double* __restrict__ chcoef,
                        const double* __restrict__ spact, float* __restrict__ out_sf,
                        float* __restrict__ out_mask, unsigned long long* __restrict__ cnt) {
  const int nth = gridDim.x * blockDim.x;
  int cl = 0;
  for (int g4 = blockIdx.x * blockDim.x + threadIdx.x; g4 < SF_ELEMS / 4; g4 += nth) {
    size_t e = (size_t)g4 * 4;
    int nc = (int)(e >> 14);
    int p = (int)(e & (HW - 1));
    int n = nc >> 8, c = nc & 255;
    f32x4 v = __builtin_nontemporal_load((const f32x4*)&feat[e]);
    f32x4 mk;
    if (n == 0) {
      mk = (f32x4){1.f, 1.f, 1.f, 1.f};
    } else {
      double cc = chcoef[(n - 1) * CCH + c];
      const double* sp = &spact[(size_t)(n - 1) * HW + p];
#pragma unroll
      for (int l = 0; l < 4; ++l) {
        float m = (cc * sp[l] > 0.01) ? 1.f : 0.f;
        mk[l] = m;
        cl += (m != 0.f);
      }
    }
    f32x4 o;
#pragma unroll
    for (int l = 0; l < 4; ++l) o[l] = v[l] * mk[l];
    __builtin_nontemporal_store(o, (f32x4*)&out_sf[e]);
    __builtin_nontemporal_store(mk, (f32x4*)&out_mask[e]);
  }
#pragma unroll
  for (int off = 32; off > 0; off >>= 1) cl += __shfl_down(cl, off);
  if ((threadIdx.x & 63) == 0 && cl > 0) atomicAdd(cnt, (unsigned long long)cl);
}

// ---------------- K7: weight conversion f32 -> bf16 ----------------
__global__ void k7_wconv(const float* __restrict__ w1, const float* __restrict__ w2,
                         unsigned short* __restrict__ W1b, unsigned short* __restrict__ W2b) {
  int gid = blockIdx.x * 256 + threadIdx.x;   // 0..1048575
  if (gid < 524288) W1b[gid] = f32_to_bf16(w1[gid]);
  W2b[gid] = f32_to_bf16(w2[gid]);
}

// ---------------- K8 v3: fused stat MLP, 1024 threads (16 waves), 64 rows -------
// Rows 0..31 = branch0 (joint: xcat = [feat[n] | sf[n]]), rows 32..63 = branch1
// (marginal: [feat[n1] | sf[n]]). Both branches share every weight load.
// Per-wave col slices: layer1 16 cols, layer2 64 cols. acc2 = 16 f32x4 = 64 regs.
// LDS: xcat 64x512 bf16 (64KB) + h1 chunk 64x256 bf16 (32KB) + t_acc = 98.5 KB.
// VGPR target <=128 -> 4 waves/SIMD, no spill.

__device__ __forceinline__ int xidx(int row, int c) {    // xcat: row-stride 512 shorts
  return row * 512 + ((((c >> 3) ^ (row & 7)) << 3) | (c & 7));
}
__device__ __forceinline__ int hidx(int row, int oc) {   // h1 chunk: row-stride 256 shorts
  return 32768 + row * 256 + ((((oc >> 3) ^ (row & 7)) << 3) | (oc & 7));
}

__global__ __launch_bounds__(1024, 4) void k8_stat(
    const float* __restrict__ feat, const float* __restrict__ sf,
    const unsigned short* __restrict__ W1b, const unsigned short* __restrict__ W2b,
    const float* __restrict__ b1, const float* __restrict__ b2,
    const float* __restrict__ w3, const float* __restrict__ b3,
    double* __restrict__ S1, double* __restrict__ S2) {
  __shared__ unsigned short lds[49280];          // 98560 B
  float* t_acc = (float*)&lds[49152];            // 64 floats

  const int bid = blockIdx.x;
  const int n = bid >> 9;                        // 512 tiles of 32 px per image
  const int p0 = (bid & 511) << 5;
  const int n1 = (n + 1 == NIMG) ? 0 : n + 1;

  const int t = threadIdx.x;                     // 1024 threads = 16 waves
  const int lane = t & 63;
  const int w = t >> 6;                          // wave 0..15
  const int n16 = lane & 15;
  const int quad = lane >> 4;

  // ---- stage xcat (nontemporal streams; weights stay hot in L2)
  {
    const int c = t & 511;
    const int half = t >> 9;                     // px sub-range
    if (t < 64) t_acc[t] = 0.f;
#pragma unroll
    for (int rb = 0; rb < 2; ++rb) {             // rb = branch row-block
      const float* s = (c < 256)
          ? feat + ((size_t)(rb ? n1 : n) * CCH + c) * HW + p0
          : sf + ((size_t)n * CCH + (c - 256)) * HW + p0;
      const f32x4* s4 = (const f32x4*)(s + half * 16);
#pragma unroll
      for (int i = 0; i < 4; ++i) {
        f32x4 v = __builtin_nontemporal_load(s4 + i);
        const int prow = rb * 32 + half * 16 + i * 4;
#pragma unroll
        for (int l = 0; l < 4; ++l) lds[xidx(prow + l, c)] = f32_to_bf16(v[l]);
      }
    }
  }
  __syncthreads();

  f32x4 acc2[4][4];
  {
    f32x4 z = {0.f, 0.f, 0.f, 0.f};
#pragma unroll
    for (int g = 0; g < 4; ++g)
#pragma unroll
      for (int jt = 0; jt < 4; ++jt) acc2[g][jt] = z;
  }

  for (int nc = 0; nc < 4; ++nc) {
    // ---- layer1 N-chunk: wave covers 16 cols; b prefetched one step ahead
    f32x4 acc1[4];
    {
      f32x4 z = {0.f, 0.f, 0.f, 0.f};
#pragma unroll
      for (int g = 0; g < 4; ++g) acc1[g] = z;
    }
    const int o = nc * 256 + w * 16 + n16;
    const unsigned short* Wrow = W1b + (size_t)o * 512;
    bf16x8 bnxt = *(const bf16x8*)&Wrow[quad * 8];
    for (int ks = 0; ks < 16; ++ks) {
      bf16x8 b = bnxt;
      if (ks < 15) bnxt = *(const bf16x8*)&Wrow[(ks + 1) * 32 + quad * 8];
      const int cb = ks * 32 + quad * 8;
#pragma unroll
      for (int g = 0; g < 4; ++g) {
        bf16x8 a = *(const bf16x8*)&lds[xidx(g * 16 + n16, cb)];
        acc1[g] = __builtin_amdgcn_mfma_f32_16x16x32_bf16(a, b, acc1[g], 0, 0, 0);
      }
    }
    __syncthreads();   // all waves done reading h1c of previous chunk

    // ---- epilogue1: bias+relu -> h1 chunk (bf16, swizzled)
    {
      const float bv = b1[o];
      const int ol = w * 16 + n16;
#pragma unroll
      for (int g = 0; g < 4; ++g) {
#pragma unroll
        for (int r = 0; r < 4; ++r) {
          const int row = g * 16 + quad * 4 + r;
          float v = acc1[g][r] + bv;
          v = v > 0.f ? v : 0.f;
          lds[hidx(row, ol)] = f32_to_bf16(v);
        }
      }
    }
    __syncthreads();

    // ---- layer2 partial: K-slice [nc*256, +256); wave covers 64 cols
    for (int ksl = 0; ksl < 8; ++ksl) {
      const int ocb = ksl * 32 + quad * 8;
      bf16x8 a[4];
#pragma unroll
      for (int g = 0; g < 4; ++g) a[g] = *(const bf16x8*)&lds[hidx(g * 16 + n16, ocb)];
#pragma unroll
      for (int jt = 0; jt < 4; ++jt) {
        const int o2 = w * 64 + jt * 16 + n16;
        bf16x8 b = *(const bf16x8*)&W2b[(size_t)o2 * 1024 + nc * 256 + ocb];
#pragma unroll
        for (int g = 0; g < 4; ++g)
          acc2[g][jt] = __builtin_amdgcn_mfma_f32_16x16x32_bf16(a[g], b, acc2[g][jt], 0, 0, 0);
      }
    }
  }

  // ---- epilogue2: relu(acc2+b2) dot w3, reduce to per-row T
  float tp[4][4];
#pragma unroll
  for (int g = 0; g < 4; ++g)
#pragma unroll
    for (int r = 0; r < 4; ++r) tp[g][r] = 0.f;
#pragma unroll
  for (int jt = 0; jt < 4; ++jt) {
    const int o2 = w * 64 + jt * 16 + n16;
    const float bv = b2[o2];
    const float wv = w3[o2];
#pragma unroll
    for (int g = 0; g < 4; ++g) {
#pragma unroll
      for (int r = 0; r < 4; ++r) {
        float v = acc2[g][jt][r] + bv;
        v = v > 0.f ? v : 0.f;
        tp[g][r] += v * wv;
      }
    }
  }
#pragma unroll
  for (int off = 1; off < 16; off <<= 1) {
#pragma unroll
    for (int g = 0; g < 4; ++g)
#pragma unroll
      for (int r = 0; r < 4; ++r) tp[g][r] += __shfl_xor(tp[g][r], off);
  }
  if (n16 == 0) {
#pragma unroll
    for (int g = 0; g < 4; ++g)
#pragma unroll
      for (int r = 0; r < 4; ++r) atomicAdd(&t_acc[g * 16 + quad * 4 + r], tp[g][r]);
  }
  __syncthreads();

  if (t < 64) {
    const float T = t_acc[t] + b3[0];
    float v = (t < 32) ? softplus_f(-T) : softplus_f(T);   // rows<32: joint, else marginal
#pragma unroll
    for (int off = 16; off > 0; off >>= 1) v += __shfl_down(v, off);
    if (t == 0) atomicAdd(S1, (double)v);
    if (t == 32) atomicAdd(S2, (double)v);
  }
}

// ---------------- K9: finalize scalars ----------------
__global__ void k9_final(const double* __restrict__ S1, const double* __restrict__ S2,
                         const unsigned long long* __restrict__ cnt, float* __restrict__ out) {
  if (threadIdx.x == 0 && blockIdx.x == 0) {
    out[LOSS_OFF] = (float)(((*S1) + (*S2)) / 81920.0);
    out[RATE_OFF] = (float)((double)(*cnt) / 16777216.0);
  }
}

extern "C" void kernel_launch(void* const* d_in, const int* in_sizes, int n_in,
                              void* d_out, int out_size, void* d_ws, size_t ws_size,
                              hipStream_t stream) {
  const float* feat     = (const float*)d_in[0];
  const float* mlp_w1   = (const float*)d_in[1];
  const float* mlp_w2   = (const float*)d_in[2];
  const float* sp_req_w = (const float*)d_in[3];
  const float* ch_fus_w = (const float*)d_in[4];
  const float* sp_fus_w = (const float*)d_in[5];
  const float* st_w1    = (const float*)d_in[6];
  const float* st_b1    = (const float*)d_in[7];
  const float* st_w2    = (const float*)d_in[8];
  const float* st_b2    = (const float*)d_in[9];
  const float* st_w3    = (const float*)d_in[10];
  const float* st_b3    = (const float*)d_in[11];
  float* out = (float*)d_out;

  char* ws = (char*)d_ws;
  double* S1     = (double*)(ws + 0);
  double* S2     = (double*)(ws + 8);
  unsigned long long* cnt = (unsigned long long*)(ws + 16);
  double* avg_d  = (double*)(ws + 64);        // 1280
  double* mx_d   = (double*)(ws + 10304);     // 1280
  double* chmean = (double*)(ws + 20544);     // 81920
  double* chmax  = (double*)(ws + 675904);    // 81920
  double* spatt  = (double*)(ws + 1331264);   // 81920
  double* actb   = (double*)(ws + 1986624);   // 81920
  double* chcoef = (double*)(ws + 2652224);   // 1024
  double* spsig  = (double*)(ws + 2660416);   // 65536
  double* spact  = (double*)(ws + 3184704);   // 65536
  unsigned short* W1b = (unsigned short*)(ws + 3708992);  // 524288
  unsigned short* W2b = (unsigned short*)(ws + 4757568);  // 1048576

  k0_init<<<1, 64, 0, stream>>>(S1, S2, cnt);
  k1_rednc<<<1280, 256, 0, stream>>>(feat, avg_d, mx_d);
  k2_rednp<<<320, 256, 0, stream>>>(feat, chmean, chmax);
  k3_chan<<<1, 256, 0, stream>>>(avg_d, mx_d, mlp_w1, mlp_w2, ch_fus_w, chcoef);
  k4_spatial<<<320, 256, 0, stream>>>(chmean, chmax, sp_req_w, spatt, actb);
  k5a_spsig<<<256, 256, 0, stream>>>(spatt, sp_fus_w, spsig);
  k5b_spcoef<<<256, 256, 0, stream>>>(spsig, actb, spact);
  k7_wconv<<<4096, 256, 0, stream>>>(st_w1, st_w2, W1b, W2b);
  k6_mask<<<2048, 256, 0, stream>>>(feat, chcoef, spact, out, out + MASK_OFF, cnt);
  k8_stat<<<2560, 1024, 0, stream>>>(feat, out, W1b, W2b, st_b1, st_b2, st_w3, st_b3, S1, S2);
  k9_final<<<1, 64, 0, stream>>>(S1, S2, cnt, out);
}